// Round 9
// baseline (161.332 us; speedup 1.0000x reference)
//
#include <hip/hip_runtime.h>
#include <stdint.h>

#define B_SZ   2
#define T_SEQ  2048
#define WIDTH_ 1024
#define NH     16
#define HD     64
#define WIN    256
#define MROWS  (B_SZ * T_SEQ)   // 4096

typedef __attribute__((ext_vector_type(4))) float f32x4;
typedef __attribute__((ext_vector_type(8))) short s16x8;

#define MFMA(a, b, c) __builtin_amdgcn_mfma_f32_16x16x32_bf16((a), (b), (c), 0, 0, 0)

__device__ __forceinline__ ushort f2bf(float f) {
  union { float f; uint32_t u; } v; v.f = f;
  uint32_t u = v.u;
  return (ushort)((u + 0x7FFFu + ((u >> 16) & 1u)) >> 16);
}

// ---------------------------------------------------------------------------
// GEMM with fused fp32->bf16 cast (prep kernel eliminated).
// C[M x N] = A * B^T. Tile 128(M) x 64(N), BK=64, 16 K-steps.
// Reg-staged (T14): global->reg loads for step t+1 issued BEFORE compute(t)
// (HBM/L2 latency hides under 16 MFMA + 6 ds_read); cvt+ds_write after the
// post-compute barrier. Single LDS buffer, stride 72 elems (144 B = 9x16 B)
// -> ds_read_b128 bank conflicts ~2-way (free) instead of 8-16-way.
// 4 waves, each owns 32(M) x 64(N) = 2x4 fragments, 16 MFMA/step.
// MODE 0: A = x (f32), B = Wq/Wk/Wv rows (f32; tile n-range is entirely
//         within one weight tensor since N-tile=64); epilogue -> qb/kb/vt.
// MODE 1: A = attn (bf16), B = Wf (f32); epilogue -> fp32 out + bias.
// ---------------------------------------------------------------------------
template <int MODE>
__global__ __launch_bounds__(256, 3) void gemm_kernel(
    const void* __restrict__ A0, const float* __restrict__ B0,
    const float* __restrict__ B1, const float* __restrict__ B2,
    ushort* __restrict__ qb, ushort* __restrict__ kb, ushort* __restrict__ vt,
    float* __restrict__ Cf, const float* __restrict__ bias) {
  const int NBX = (MODE == 0) ? 18 : 16;
  const int nwg = NBX * 32;              // 576 / 512, both % 8 == 0
  const int cpx = nwg >> 3;
  int swz = ((int)blockIdx.x & 7) * cpx + ((int)blockIdx.x >> 3);
  const int bx = swz % NBX;
  const int by = swz / NBX;

  const int tid = threadIdx.x;
  const int w = tid >> 6;
  const int lane = tid & 63;
  const int g = lane >> 4;
  const int r16 = lane & 15;
  const int m0 = by * 128;
  const int n0 = bx * 64;
  const int wm = w * 32;                 // wave's 32 M-rows

  // B row-0 pointer for this tile (block-uniform)
  const float* Brow;
  if (MODE == 0)
    Brow = (bx < 16) ? B0 + (size_t)n0 * 1024 : (bx == 16 ? B1 : B2);
  else
    Brow = B0 + (size_t)n0 * 1024;

  __shared__ ushort As[128 * 72];        // 18 KiB
  __shared__ ushort Bs[64 * 72];         //  9 KiB

  f32x4 acc[2][4] = {};

  // staging registers (held across compute; single set, WAR-ordered)
  f32x4 aRf[8];                          // MODE 0 A (f32)
  s16x8 aRh[4];                          // MODE 1 A (bf16)
  f32x4 bR[4];                           // B (f32, both modes)

#define LOAD_A(K) do {                                                      \
  if (MODE == 0) {                                                          \
    const float* xp = (const float*)A0;                                     \
    _Pragma("unroll")                                                       \
    for (int i_ = 0; i_ < 8; ++i_) {                                        \
      int q_ = tid + i_ * 256;           /* 0..2047 */                      \
      int rt_ = q_ >> 4, c4_ = q_ & 15;                                     \
      aRf[i_] = *(const f32x4*)(xp + (size_t)(m0 + rt_) * 1024 + (K) +      \
                                c4_ * 4);                                   \
    }                                                                       \
  } else {                                                                  \
    const ushort* ap = (const ushort*)A0;                                   \
    _Pragma("unroll")                                                       \
    for (int i_ = 0; i_ < 4; ++i_) {                                        \
      int q_ = tid + i_ * 256;           /* 0..1023 */                      \
      int rt_ = q_ >> 3, c8_ = q_ & 7;                                      \
      aRh[i_] = *(const s16x8*)(ap + (size_t)(m0 + rt_) * 1024 + (K) +      \
                                c8_ * 8);                                   \
    }                                                                       \
  }                                                                         \
} while (0)

#define LOAD_B(K) do {                                                      \
  _Pragma("unroll")                                                         \
  for (int i_ = 0; i_ < 4; ++i_) {                                          \
    int q_ = tid + i_ * 256;             /* 0..1023 */                      \
    int rt_ = q_ >> 4, c4_ = q_ & 15;                                       \
    bR[i_] = *(const f32x4*)(Brow + (size_t)rt_ * 1024 + (K) + c4_ * 4);    \
  }                                                                         \
} while (0)

#define STORE_AB() do {                                                     \
  if (MODE == 0) {                                                          \
    _Pragma("unroll")                                                       \
    for (int i_ = 0; i_ < 8; ++i_) {                                        \
      int q_ = tid + i_ * 256;                                              \
      int rt_ = q_ >> 4, c4_ = q_ & 15;                                     \
      ushort4 o_;                                                           \
      o_.x = f2bf(aRf[i_][0]); o_.y = f2bf(aRf[i_][1]);                     \
      o_.z = f2bf(aRf[i_][2]); o_.w = f2bf(aRf[i_][3]);                     \
      *(ushort4*)&As[rt_ * 72 + c4_ * 4] = o_;                              \
    }                                                                       \
  } else {                                                                  \
    _Pragma("unroll")                                                       \
    for (int i_ = 0; i_ < 4; ++i_) {                                        \
      int q_ = tid + i_ * 256;                                              \
      int rt_ = q_ >> 3, c8_ = q_ & 7;                                      \
      *(s16x8*)&As[rt_ * 72 + c8_ * 8] = aRh[i_];                           \
    }                                                                       \
  }                                                                         \
  _Pragma("unroll")                                                         \
  for (int i_ = 0; i_ < 4; ++i_) {                                          \
    int q_ = tid + i_ * 256;                                                \
    int rt_ = q_ >> 4, c4_ = q_ & 15;                                       \
    ushort4 o_;                                                             \
    o_.x = f2bf(bR[i_][0]); o_.y = f2bf(bR[i_][1]);                         \
    o_.z = f2bf(bR[i_][2]); o_.w = f2bf(bR[i_][3]);                         \
    *(ushort4*)&Bs[rt_ * 72 + c4_ * 4] = o_;                                \
  }                                                                         \
} while (0)

#define COMPUTE() do {                                                      \
  _Pragma("unroll")                                                         \
  for (int ks_ = 0; ks_ < 2; ++ks_) {                                       \
    s16x8 af_[2], bf_[4];                                                   \
    _Pragma("unroll")                                                       \
    for (int mb_ = 0; mb_ < 2; ++mb_)                                       \
      af_[mb_] = *(const s16x8*)&As[(wm + mb_ * 16 + r16) * 72 +            \
                                    ks_ * 32 + g * 8];                      \
    _Pragma("unroll")                                                       \
    for (int nb_ = 0; nb_ < 4; ++nb_)                                       \
      bf_[nb_] = *(const s16x8*)&Bs[(nb_ * 16 + r16) * 72 +                 \
                                    ks_ * 32 + g * 8];                      \
    _Pragma("unroll")                                                       \
    for (int mb_ = 0; mb_ < 2; ++mb_)                                       \
      _Pragma("unroll")                                                     \
      for (int nb_ = 0; nb_ < 4; ++nb_)                                     \
        acc[mb_][nb_] = MFMA(af_[mb_], bf_[nb_], acc[mb_][nb_]);            \
  }                                                                         \
} while (0)

  LOAD_A(0); LOAD_B(0);
  STORE_AB();                            // compiler waits the loads here
  __syncthreads();
  for (int k0 = 0; k0 < 1024; k0 += 64) {
    const bool more = (k0 + 64 < 1024);
    if (more) { LOAD_A(k0 + 64); LOAD_B(k0 + 64); }   // issue early (T14)
    COMPUTE();
    __syncthreads();                     // all waves done reading LDS
    if (more) {
      STORE_AB();                        // cvt+write next tile
      __syncthreads();                   // writes visible before next reads
    }
  }

  // epilogue: C/D layout col = r16, row = 4*g + r
#pragma unroll
  for (int mb = 0; mb < 2; ++mb)
#pragma unroll
    for (int nb = 0; nb < 4; ++nb) {
      int n = n0 + nb * 16 + r16;
      int mbase = m0 + wm + mb * 16 + 4 * g;
      if (MODE == 0) {
        if (bx < 16) {
#pragma unroll
          for (int r = 0; r < 4; ++r)
            qb[(mbase + r) * 1024 + n] = f2bf(acc[mb][nb][r]);
        } else if (bx == 16) {
#pragma unroll
          for (int r = 0; r < 4; ++r)
            kb[(mbase + r) * 64 + (n & 63)] = f2bf(acc[mb][nb][r]);
        } else {
#pragma unroll
          for (int r = 0; r < 4; ++r) {
            int m = mbase + r;
            vt[((size_t)((m >> 11) * 64 + (n & 63))) * 2048 + (m & 2047)] =
                f2bf(acc[mb][nb][r]);
          }
        }
      } else {
        float bv = bias[n];
#pragma unroll
        for (int r = 0; r < 4; ++r)
          Cf[(size_t)(mbase + r) * 1024 + n] = acc[mb][nb][r] + bv;
      }
    }
#undef LOAD_A
#undef LOAD_B
#undef STORE_AB
#undef COMPUTE
}

// ---------------------------------------------------------------------------
// Sliding-window attention, KVBLK=64 (byte-identical to r8).
// ---------------------------------------------------------------------------
__global__ __launch_bounds__(64, 2) void attn_kernel(
    const ushort* __restrict__ qb, const ushort* __restrict__ kb,
    const ushort* __restrict__ vt, ushort* __restrict__ ao) {
  const int lane = threadIdx.x;
  const int g = lane >> 4;
  const int r16 = lane & 15;
  const int blk = blockIdx.x;            // b*1024 + h*64 + qt
  const int qt = blk & 63;
  const int h = (blk >> 6) & 15;
  const int b = blk >> 10;
  const int q0 = qt * 32;
  const int qpA = q0 + r16;
  const int qpB = q0 + 16 + r16;

  const ushort* qrowA = qb + (size_t)(b * 2048 + qpA) * 1024 + h * 64;
  const ushort* qrowB = qb + (size_t)(b * 2048 + qpB) * 1024 + h * 64;
  s16x8 qfA0 = *(const s16x8*)(qrowA + g * 8);
  s16x8 qfA1 = *(const s16x8*)(qrowA + 32 + g * 8);
  s16x8 qfB0 = *(const s16x8*)(qrowB + g * 8);
  s16x8 qfB1 = *(const s16x8*)(qrowB + 32 + g * 8);

  f32x4 oaccA[4] = {}, oaccB[4] = {};
  float mA = -1e30f, lA = 0.f, mB = -1e30f, lB = 0.f;

  int kt0 = q0 - WIN;
  if (kt0 < 0) kt0 = 0;
  kt0 &= ~31;

  s16x8 pk[4][2];
#pragma unroll
  for (int s = 0; s < 4; ++s) {
    const ushort* kp = kb + (size_t)(b * 2048 + kt0 + s * 16 + r16) * 64;
    pk[s][0] = *(const s16x8*)(kp + g * 8);
    pk[s][1] = *(const s16x8*)(kp + 32 + g * 8);
  }

  for (int kt = kt0; kt <= q0; kt += 64) {
    s16x8 c[4][2];
#pragma unroll
    for (int s = 0; s < 4; ++s) { c[s][0] = pk[s][0]; c[s][1] = pk[s][1]; }

    s16x8 vfr[4][2];
#pragma unroll
    for (int db = 0; db < 4; ++db) {
      const ushort* vrow = vt + (size_t)(b * 64 + db * 16 + r16) * 2048 + kt;
      uint2 va0 = *(const uint2*)(vrow + 4 * g);
      uint2 va1 = *(const uint2*)(vrow + 16 + 4 * g);
      uint2 vb0 = *(const uint2*)(vrow + 32 + 4 * g);
      uint2 vb1 = *(const uint2*)(vrow + 48 + 4 * g);
      union { s16x8 v; uint32_t d[4]; } u0, u1;
      u0.d[0] = va0.x; u0.d[1] = va0.y; u0.d[2] = va1.x; u0.d[3] = va1.y;
      u1.d[0] = vb0.x; u1.d[1] = vb0.y; u1.d[2] = vb1.x; u1.d[3] = vb1.y;
      vfr[db][0] = u0.v; vfr[db][1] = u1.v;
    }

    if (kt + 64 <= q0) {
#pragma unroll
      for (int s = 0; s < 4; ++s) {
        const ushort* kp = kb + (size_t)(b * 2048 + kt + 64 + s * 16 + r16) * 64;
        pk[s][0] = *(const s16x8*)(kp + g * 8);
        pk[s][1] = *(const s16x8*)(kp + 32 + g * 8);
      }
    }

    f32x4 sA[4], sB[4];
    __builtin_amdgcn_s_setprio(1);
#pragma unroll
    for (int s = 0; s < 4; ++s) {
      f32x4 z = {};
      sA[s] = MFMA(c[s][0], qfA0, z); sA[s] = MFMA(c[s][1], qfA1, sA[s]);
      sB[s] = MFMA(c[s][0], qfB0, z); sB[s] = MFMA(c[s][1], qfB1, sB[s]);
    }
    __builtin_amdgcn_s_setprio(0);

    float pA[4][4], pB[4][4];
    float tmA = -1e30f, tmB = -1e30f;
#pragma unroll
    for (int s = 0; s < 4; ++s)
#pragma unroll
      for (int r = 0; r < 4; ++r) {
        int ka = kt + s * 16 + 4 * g + r;
        float a = (ka <= qpA && qpA - ka <= WIN) ? sA[s][r] * 0.125f : -1e30f;
        float bv = (ka <= qpB && qpB - ka <= WIN) ? sB[s][r] * 0.125f : -1e30f;
        pA[s][r] = a; pB[s][r] = bv;
        tmA = fmaxf(tmA, a); tmB = fmaxf(tmB, bv);
      }
    tmA = fmaxf(tmA, __shfl_xor(tmA, 16));
    tmA = fmaxf(tmA, __shfl_xor(tmA, 32));
    tmB = fmaxf(tmB, __shfl_xor(tmB, 16));
    tmB = fmaxf(tmB, __shfl_xor(tmB, 32));

    float mnA = fmaxf(mA, tmA), mnB = fmaxf(mB, tmB);
    float corrA = __expf(mA - mnA), corrB = __expf(mB - mnB);
    float tsA = 0.f, tsB = 0.f;
    s16x8 pfA0, pfA1, pfB0, pfB1;
#pragma unroll
    for (int r = 0; r < 4; ++r) {
      float eA0 = __expf(pA[0][r] - mnA);
      float eA1 = __expf(pA[1][r] - mnA);
      float eA2 = __expf(pA[2][r] - mnA);
      float eA3 = __expf(pA[3][r] - mnA);
      float eB0 = __expf(pB[0][r] - mnB);
      float eB1 = __expf(pB[1][r] - mnB);
      float eB2 = __expf(pB[2][r] - mnB);
      float eB3 = __expf(pB[3][r] - mnB);
      tsA += (eA0 + eA1) + (eA2 + eA3);
      tsB += (eB0 + eB1) + (eB2 + eB3);
      pfA0[r] = (short)f2bf(eA0); pfA0[4 + r] = (short)f2bf(eA1);
      pfA1[r] = (short)f2bf(eA2); pfA1[4 + r] = (short)f2bf(eA3);
      pfB0[r] = (short)f2bf(eB0); pfB0[4 + r] = (short)f2bf(eB1);
      pfB1[r] = (short)f2bf(eB2); pfB1[4 + r] = (short)f2bf(eB3);
    }
    tsA += __shfl_xor(tsA, 16); tsA += __shfl_xor(tsA, 32);
    tsB += __shfl_xor(tsB, 16); tsB += __shfl_xor(tsB, 32);
    lA = lA * corrA + tsA; mA = mnA;
    lB = lB * corrB + tsB; mB = mnB;

#pragma unroll
    for (int db = 0; db < 4; ++db) { oaccA[db] *= corrA; oaccB[db] *= corrB; }

    __builtin_amdgcn_s_setprio(1);
#pragma unroll
    for (int db = 0; db < 4; ++db) {
      oaccA[db] = MFMA(vfr[db][0], pfA0, oaccA[db]);
      oaccA[db] = MFMA(vfr[db][1], pfA1, oaccA[db]);
      oaccB[db] = MFMA(vfr[db][0], pfB0, oaccB[db]);
      oaccB[db] = MFMA(vfr[db][1], pfB1, oaccB[db]);
    }
    __builtin_amdgcn_s_setprio(0);
  }

  float invA = 1.0f / lA, invB = 1.0f / lB;
  ushort* orowA = ao + (size_t)(b * 2048 + qpA) * 1024 + h * 64;
  ushort* orowB = ao + (size_t)(b * 2048 + qpB) * 1024 + h * 64;
#pragma unroll
  for (int db = 0; db < 4; ++db) {
    ushort4 oA, oB;
    oA.x = f2bf(oaccA[db][0] * invA); oA.y = f2bf(oaccA[db][1] * invA);
    oA.z = f2bf(oaccA[db][2] * invA); oA.w = f2bf(oaccA[db][3] * invA);
    oB.x = f2bf(oaccB[db][0] * invB); oB.y = f2bf(oaccB[db][1] * invB);
    oB.z = f2bf(oaccB[db][2] * invB); oB.w = f2bf(oaccB[db][3] * invB);
    *(ushort4*)(orowA + db * 16 + 4 * g) = oA;
    *(ushort4*)(orowB + db * 16 + 4 * g) = oB;
  }
}

// ---------------------------------------------------------------------------
extern "C" void kernel_launch(void* const* d_in, const int* in_sizes, int n_in,
                              void* d_out, int out_size, void* d_ws, size_t ws_size,
                              hipStream_t stream) {
  const float* x  = (const float*)d_in[0];
  // d_in[1] = segment_pos (unused; reference masks with arange)
  const float* Wq = (const float*)d_in[2];
  const float* Wk = (const float*)d_in[3];
  const float* Wv = (const float*)d_in[4];
  const float* Wf = (const float*)d_in[5];
  const float* bf = (const float*)d_in[6];
  float* out = (float*)d_out;

  uint8_t* w8 = (uint8_t*)d_ws;
  ushort* qbuf = (ushort*)(w8 + 0);          //  8 MiB  q bf16 (4096x1024)
  ushort* attn = (ushort*)(w8 + 8388608);    //  8 MiB  attn out bf16
  ushort* kbuf = (ushort*)(w8 + 16777216);   //  512 KiB (4096x64)
  ushort* vt   = (ushort*)(w8 + 17301504);   //  512 KiB (b, 64, 2048)
  // attn's masked tail K/V reads may run up to ~64 B past kbuf/vt ends; they
  // land inside the (much larger) workspace and are multiplied by P == 0.

  gemm_kernel<0><<<576, 256, 0, stream>>>(x, Wq, Wk, Wv,
                                          qbuf, kbuf, vt, nullptr, nullptr);
  attn_kernel<<<2048, 64, 0, stream>>>(qbuf, kbuf, vt, attn);
  gemm_kernel<1><<<512, 256, 0, stream>>>(attn, Wf, nullptr, nullptr,
                                          nullptr, nullptr, nullptr, out, bf);
}